// Round 3
// baseline (261.951 us; speedup 1.0000x reference)
//
#include <hip/hip_runtime.h>

// SparseMaxPool: out[b,d,r,c] = max(x[b,d,r..c]) on sparse (r,c), else 0.
// R3: bank-aligned value-array layout. Entry key = (c, s), s<40 segments.
//   addr(c,s) = VOFF2 + (c>>2) + 32*((c&3)*40 + s)  ->  bank = c>>2.
// Output gather wave-inst: lanes j=0..31 have distinct banks j (c=4j+comp),
// rows r/r+1 give 2 lanes/bank = free on CDNA4. Invalid -> per-bank zero slot.

#define NN 128
#define SLICE_ELEMS (NN * NN)
#define VOFF2 800            // value region base (doubling table occupies 0..776); %32==0
#define ZBASE 5920           // 32 per-bank zero slots; %32==0
#define SCRATCH 5952         // dump slot for pad build items
#define LDS_WORDS 5956
#define NBUILD 2560          // 2548 real + 12 pad
#define NODESC 16384

__device__ __forceinline__ void seg_params(int s, int& o, int& sh) {
    if (s < 16)      { o = s;                 sh = 0; }
    else if (s < 24) { o = 17 + 2 * (s - 16); sh = 1; }
    else if (s < 32) { o = 35 + 4 * (s - 24); sh = 2; }
    else             { o = 71 + 8 * (s - 32); sh = 3; }
}

__device__ __forceinline__ int val_addr(int c, int s) {
    return VOFF2 + (c >> 2) + (((c & 3) * 40 + s) << 5);
}

__global__ __launch_bounds__(256) void sp_init(unsigned int* __restrict__ bdesc,
                                               unsigned short* __restrict__ odesc) {
    int idx = blockIdx.x * 256 + threadIdx.x;
    if (idx < NODESC) {
        int r = idx >> 7, c = idx & 127;
        int o = c - r;
        int sh = -1, s = 0;
        if (o >= 0 && o <= 15)                         { sh = 0; s = o; }
        else if (o >= 17 && o <= 31 && (o & 1) == 1)   { sh = 1; s = 16 + ((o - 17) >> 1); }
        else if (o >= 35 && o <= 63 && (o & 3) == 3)   { sh = 2; s = 24 + ((o - 35) >> 2); }
        else if (o >= 71 && o <= 127 && (o & 7) == 7)  { sh = 3; s = 32 + ((o - 71) >> 3); }
        unsigned short addr = (unsigned short)(ZBASE + (c >> 2)); // per-bank zero slot
        if (sh >= 0 && (r & ((1 << sh) - 1)) == 0)
            addr = (unsigned short)val_addr(c, s);
        odesc[idx] = addr;
    } else if (idx < NODESC + NBUILD) {
        int i = idx - NODESC;
        unsigned int desc = (unsigned)SCRATCH << 16;   // pad: read buf[0], write scratch
        int base = 0;
        for (int t = 0; t < 40; ++t) {
            int oo, ss; seg_params(t, oo, ss);
            int cnt = ((127 - oo) >> ss) + 1;
            if (i < base + cnt) {
                int r = (i - base) << ss;
                int c = r + oo;
                int w = oo + 1;
                int k = 31 - __clz(w);
                int p2 = 1 << k;
                int lb = 129 * k - (p2 - 1);          // doubling-level base
                int s1 = lb + r;                      // <= 776+127 < 1024
                int d2 = w - p2;                      // <= 63
                int dest = val_addr(c, t);            // < 5920 (13 bits)
                desc = (unsigned)s1 | ((unsigned)d2 << 10) | ((unsigned)dest << 16);
                break;
            }
            base += cnt;
        }
        bdesc[i] = desc;
    }
}

__global__ __launch_bounds__(256) void sp_main(const float* __restrict__ x,
                                               float* __restrict__ out,
                                               const unsigned int* __restrict__ bdesc,
                                               const unsigned short* __restrict__ odesc) {
    __shared__ float buf[LDS_WORDS];
    const int tid = threadIdx.x;
    const int slice = blockIdx.x;

    if (tid < NN) buf[tid] = x[(size_t)slice * NN + tid];
    else if (tid >= 128 && tid < 160) buf[ZBASE + (tid - 128)] = 0.0f;
    __syncthreads();

    // Doubling table levels 1..7: P[k][i] = max(P[k-1][i], P[k-1][i+2^{k-1}])
    int base_prev = 0, base_cur = NN;
    #pragma unroll
    for (int k = 1; k <= 7; ++k) {
        int half = 1 << (k - 1);
        int len = (NN + 1) - (1 << k);
        if (tid < len)
            buf[base_cur + tid] = fmaxf(buf[base_prev + tid], buf[base_prev + tid + half]);
        __syncthreads();
        base_prev = base_cur;
        base_cur += len;
    }

    // Build value array into bank-aligned layout (2548 entries + 12 pad)
    #pragma unroll
    for (int it = 0; it < NBUILD / 256; ++it) {
        int i = it * 256 + tid;
        unsigned int d = bdesc[i];
        int s1 = d & 1023;
        int d2 = (d >> 10) & 63;
        int dest = d >> 16;
        buf[dest] = fmaxf(buf[s1], buf[s1 + d2]);
    }
    __syncthreads();

    // Output: 4096 float4/slice, 16/thread; each component read is conflict-free
    float4* __restrict__ out_s = reinterpret_cast<float4*>(out + (size_t)slice * SLICE_ELEMS);
    const uint2* __restrict__ od = reinterpret_cast<const uint2*>(odesc);
    #pragma unroll
    for (int it = 0; it < 16; ++it) {
        int idx = it * 256 + tid;
        uint2 d = od[idx];
        float4 v;
        v.x = buf[d.x & 0xffff];
        v.y = buf[d.x >> 16];
        v.z = buf[d.y & 0xffff];
        v.w = buf[d.y >> 16];
        out_s[idx] = v;
    }
}

extern "C" void kernel_launch(void* const* d_in, const int* in_sizes, int n_in,
                              void* d_out, int out_size, void* d_ws, size_t ws_size,
                              hipStream_t stream) {
    const float* x = (const float*)d_in[0];
    float* out = (float*)d_out;
    unsigned int* bdesc = (unsigned int*)d_ws;                            // 2560*4 B
    unsigned short* odesc = (unsigned short*)((char*)d_ws + NBUILD * 4);  // 16384*2 B

    const int init_items = NODESC + NBUILD;
    sp_init<<<dim3((init_items + 255) / 256), dim3(256), 0, stream>>>(bdesc, odesc);

    const int slices = in_sizes[0] / NN;   // 4096
    sp_main<<<dim3(slices), dim3(256), 0, stream>>>(x, out, bdesc, odesc);
}